// Round 5
// baseline (308.470 us; speedup 1.0000x reference)
//
#include <hip/hip_runtime.h>
#include <hip/hip_bf16.h>

#define C 32
#define R 8

typedef unsigned int u32;
__device__ __forceinline__ float bflo(u32 u) { return __uint_as_float(u << 16); }
__device__ __forceinline__ float bfhi(u32 u) { return __uint_as_float(u & 0xffff0000u); }

// ---- M[r][c][j] = sum_o W_tp[c][r][o] * W1[r*C+o][j]   (f32, 32 KB) ----
__global__ void k_prepM(const float* __restrict__ Wtp, const float* __restrict__ W1,
                        float* __restrict__ M) {
    int idx = blockIdx.x * 256 + threadIdx.x;
    if (idx >= R * C * C) return;
    int r = idx >> 10;
    int c = (idx >> 5) & 31;
    int j = idx & 31;
    float acc = 0.f;
#pragma unroll
    for (int o = 0; o < C; ++o)
        acc = fmaf(Wtp[c * R * C + r * C + o], W1[(r * C + o) * C + j], acc);
    M[idx] = acc;
}

// ---- z[n][j][r] = sum_c x[n][c] * M[r][c][j]  (bf16; r contiguous) ----
__global__ void k_nodeZ(const float* __restrict__ x, const float* __restrict__ M,
                        __hip_bfloat16* __restrict__ z, int N, int npb) {
    int t = threadIdx.x;
    int r = t & 7, j = t >> 3;
    float m[C];
#pragma unroll
    for (int c = 0; c < C; ++c) m[c] = M[r * C * C + c * C + j];
    int n0 = blockIdx.x * npb;
    int n1 = n0 + npb;
    if (n1 > N) n1 = N;
    for (int n = n0; n < n1; ++n) {
        const float* xp = x + (size_t)n * C;
        float acc = 0.f;
#pragma unroll
        for (int c = 0; c < C; ++c) acc = fmaf(xp[c], m[c], acc);
        z[(size_t)n * (R * C) + t] = __float2bfloat16(acc);
    }
}

// rbf: centers = linspace(0,5,8), width = 5/7, scaling = 1/sqrt(2pi)
__device__ __forceinline__ float rbf_lane(float dist, int r) {
    float t = (dist - 0.71428573f * (float)r) * 1.3999999f;
    return 0.3989423f * __expf(-0.5f * t * t);
}

// ---- CSR build ----
__global__ void k_hist(const int* __restrict__ ei, int* __restrict__ hist, int E, int N) {
    int i = blockIdx.x * blockDim.x + threadIdx.x;
    int stride = gridDim.x * blockDim.x;
    for (; i < E; i += stride) {
        int r = ei[i];
        r = ((unsigned)r < (unsigned)N) ? r : 0;
        atomicAdd(&hist[r], 1);
    }
}

// single-block exclusive scan: rowptr[0..N-1], rowptr[N]=E, cursor=rowptr copy
__global__ void k_scan(const int* __restrict__ hist, int* __restrict__ rowptr,
                       int* __restrict__ cursor, int N, int E) {
    __shared__ int sums[1024];
    int t = threadIdx.x;
    int CH = (N + 1023) >> 10;
    int a0 = t * CH;
    int a1 = a0 + CH; if (a1 > N) a1 = N;
    int s = 0;
    for (int a = a0; a < a1; ++a) s += hist[a];
    sums[t] = s;
    __syncthreads();
    for (int off = 1; off < 1024; off <<= 1) {
        int v = (t >= off) ? sums[t - off] : 0;
        __syncthreads();
        sums[t] += v;
        __syncthreads();
    }
    int run = (t == 0) ? 0 : sums[t - 1];
    for (int a = a0; a < a1; ++a) {
        rowptr[a] = run;
        cursor[a] = run;
        run += hist[a];
    }
    if (t == 1023) rowptr[N] = E;
}

__global__ void k_scatter(const int* __restrict__ ei, int* __restrict__ cursor,
                          int* __restrict__ csr_col, int E, int N) {
    int i = blockIdx.x * blockDim.x + threadIdx.x;
    int stride = gridDim.x * blockDim.x;
    for (; i < E; i += stride) {
        int r = ei[i];
        int cc = ei[E + i];
        r  = ((unsigned)r  < (unsigned)N) ? r  : 0;
        cc = ((unsigned)cc < (unsigned)N) ? cc : 0;
        int p = atomicAdd(&cursor[r], 1);
        csr_col[p] = cc;
    }
}

// ---- per-row edge kernel: 32 lanes = one row; fused W2/b2 epilogue + residual ----
__global__ void k_edge_csr(const int* __restrict__ rowptr, const int* __restrict__ csr_col,
                           const float* __restrict__ pos, const __hip_bfloat16* __restrict__ z,
                           const float* __restrict__ x, const float* __restrict__ b1,
                           const float* __restrict__ W2, const float* __restrict__ b2,
                           float* __restrict__ out, int N) {
    __shared__ float W2s[C * C];
    for (int i = threadIdx.x; i < C * C; i += blockDim.x) W2s[i] = W2[i];
    __syncthreads();
    int gt = blockIdx.x * blockDim.x + threadIdx.x;
    int j = gt & 31;
    int n = gt >> 5;
    if (n >= N) return;
    int p0 = rowptr[n];
    int p1 = rowptr[n + 1];
    float px = pos[n * 3 + 0], py = pos[n * 3 + 1], pz = pos[n * 3 + 2];
    float b1j = b1[j];
    int rr = j & 7;
    float acc = 0.f;
    int p = p0;
    for (; p + 1 < p1; p += 2) {
        int ca = csr_col[p];
        int cb = csr_col[p + 1];
        uint4 va = ((const uint4*)(z + (size_t)ca * (R * C)))[j];
        uint4 vb = ((const uint4*)(z + (size_t)cb * (R * C)))[j];
        float dax = px - pos[ca * 3 + 0], day = py - pos[ca * 3 + 1], daz = pz - pos[ca * 3 + 2];
        float dbx = px - pos[cb * 3 + 0], dby = py - pos[cb * 3 + 1], dbz = pz - pos[cb * 3 + 2];
        float da = sqrtf(fmaf(dax, dax, fmaf(day, day, daz * daz)) + 1e-12f);
        float db = sqrtf(fmaf(dbx, dbx, fmaf(dby, dby, dbz * dbz)) + 1e-12f);
        float ra = rbf_lane(da, rr);
        float rb = rbf_lane(db, rr);
        float ha = b1j, hb = b1j;
        ha = fmaf(__shfl(ra, 0, 32), bflo(va.x), ha);
        ha = fmaf(__shfl(ra, 1, 32), bfhi(va.x), ha);
        ha = fmaf(__shfl(ra, 2, 32), bflo(va.y), ha);
        ha = fmaf(__shfl(ra, 3, 32), bfhi(va.y), ha);
        ha = fmaf(__shfl(ra, 4, 32), bflo(va.z), ha);
        ha = fmaf(__shfl(ra, 5, 32), bfhi(va.z), ha);
        ha = fmaf(__shfl(ra, 6, 32), bflo(va.w), ha);
        ha = fmaf(__shfl(ra, 7, 32), bfhi(va.w), ha);
        hb = fmaf(__shfl(rb, 0, 32), bflo(vb.x), hb);
        hb = fmaf(__shfl(rb, 1, 32), bfhi(vb.x), hb);
        hb = fmaf(__shfl(rb, 2, 32), bflo(vb.y), hb);
        hb = fmaf(__shfl(rb, 3, 32), bfhi(vb.y), hb);
        hb = fmaf(__shfl(rb, 4, 32), bflo(vb.z), hb);
        hb = fmaf(__shfl(rb, 5, 32), bfhi(vb.z), hb);
        hb = fmaf(__shfl(rb, 6, 32), bflo(vb.w), hb);
        hb = fmaf(__shfl(rb, 7, 32), bfhi(vb.w), hb);
        acc += ha / (1.f + __expf(-ha)) + hb / (1.f + __expf(-hb));
    }
    if (p < p1) {
        int ca = csr_col[p];
        uint4 va = ((const uint4*)(z + (size_t)ca * (R * C)))[j];
        float dax = px - pos[ca * 3 + 0], day = py - pos[ca * 3 + 1], daz = pz - pos[ca * 3 + 2];
        float da = sqrtf(fmaf(dax, dax, fmaf(day, day, daz * daz)) + 1e-12f);
        float ra = rbf_lane(da, rr);
        float ha = b1j;
        ha = fmaf(__shfl(ra, 0, 32), bflo(va.x), ha);
        ha = fmaf(__shfl(ra, 1, 32), bfhi(va.x), ha);
        ha = fmaf(__shfl(ra, 2, 32), bflo(va.y), ha);
        ha = fmaf(__shfl(ra, 3, 32), bfhi(va.y), ha);
        ha = fmaf(__shfl(ra, 4, 32), bflo(va.z), ha);
        ha = fmaf(__shfl(ra, 5, 32), bfhi(va.z), ha);
        ha = fmaf(__shfl(ra, 6, 32), bflo(va.w), ha);
        ha = fmaf(__shfl(ra, 7, 32), bfhi(va.w), ha);
        acc += ha / (1.f + __expf(-ha));
    }
    // epilogue: out[n][j] = x[n][j] + sum_i acc_i * W2[i][j] + deg * b2[j]
    float v = fmaf((float)(p1 - p0), b2[j], x[(size_t)n * C + j]);
#pragma unroll
    for (int i = 0; i < C; ++i)
        v = fmaf(__shfl(acc, i, 32), W2s[i * C + j], v);
    out[(size_t)n * C + j] = v;
}

// ---- Tier B kernels (proven fallback) ----
__global__ void k_edge_direct(const int* __restrict__ ei, const float* __restrict__ pos,
                              const float* __restrict__ x, const float* __restrict__ M,
                              const float* __restrict__ b1,
                              float* __restrict__ agg, float* __restrict__ deg,
                              int E, int N) {
    __shared__ float Ms[R * C * C];
    for (int i = threadIdx.x; i < R * C * C; i += blockDim.x) Ms[i] = M[i];
    __syncthreads();
    int gt = blockIdx.x * blockDim.x + threadIdx.x;
    int j = gt & 31;
    int g = gt >> 5;
    int ngroups = (gridDim.x * blockDim.x) >> 5;
    float b1j = b1[j];
    for (int e = g; e < E; e += ngroups) {
        int row = ei[e];
        int col = ei[E + e];
        row = ((unsigned)row < (unsigned)N) ? row : 0;
        col = ((unsigned)col < (unsigned)N) ? col : 0;
        float dx = pos[row * 3 + 0] - pos[col * 3 + 0];
        float dy = pos[row * 3 + 1] - pos[col * 3 + 1];
        float dz = pos[row * 3 + 2] - pos[col * 3 + 2];
        float dist = sqrtf(fmaf(dx, dx, fmaf(dy, dy, dz * dz)) + 1e-12f);
        float my_rbf = rbf_lane(dist, j & 7);
        float xr[C];
#pragma unroll
        for (int c = 0; c < C; ++c) xr[c] = x[(size_t)col * C + c];
        float h = b1j;
#pragma unroll
        for (int r = 0; r < R; ++r) {
            float s = 0.f;
#pragma unroll
            for (int c = 0; c < C; ++c)
                s = fmaf(xr[c], Ms[r * C * C + c * C + j], s);
            h = fmaf(__shfl(my_rbf, r, 32), s, h);
        }
        float sh = h / (1.f + __expf(-h));
        atomicAdd(&agg[(size_t)row * C + j], sh);
        if (j == 0) atomicAdd(&deg[row], 1.f);
    }
}

__global__ void k_final(const float* __restrict__ x, const float* __restrict__ agg,
                        const float* __restrict__ deg, const float* __restrict__ W2,
                        const float* __restrict__ b2, float* __restrict__ out,
                        int N) {
    int t = threadIdx.x;
    int j = t & 31;
    float w2[C];
#pragma unroll
    for (int i = 0; i < C; ++i) w2[i] = W2[i * C + j];
    float b2j = b2[j];
    int g = (blockIdx.x * blockDim.x + t) >> 5;
    int ngroups = (gridDim.x * blockDim.x) >> 5;
    for (int n = g; n < N; n += ngroups) {
        const float* ap = agg + (size_t)n * C;
        float acc = 0.f;
#pragma unroll
        for (int i = 0; i < C; ++i) acc = fmaf(ap[i], w2[i], acc);
        out[(size_t)n * C + j] = x[(size_t)n * C + j] + acc + deg[n] * b2j;
    }
}

// ---- Tier C (no usable ws) ----
__global__ void k_edge_full(const int* __restrict__ ei, const float* __restrict__ pos,
                            const float* __restrict__ x,
                            const float* __restrict__ Wtp, const float* __restrict__ W1,
                            const float* __restrict__ b1,
                            const float* __restrict__ W2, const float* __restrict__ b2,
                            float* __restrict__ out, int E, int N) {
    __shared__ float Ms[R * C * C];
    __shared__ float W2s[C * C];
    for (int idx = threadIdx.x; idx < R * C * C; idx += blockDim.x) {
        int r = idx >> 10, c = (idx >> 5) & 31, jj = idx & 31;
        float acc = 0.f;
#pragma unroll
        for (int o = 0; o < C; ++o)
            acc = fmaf(Wtp[c * R * C + r * C + o], W1[(r * C + o) * C + jj], acc);
        Ms[idx] = acc;
    }
    for (int idx = threadIdx.x; idx < C * C; idx += blockDim.x) W2s[idx] = W2[idx];
    __syncthreads();
    int gt = blockIdx.x * blockDim.x + threadIdx.x;
    int j = gt & 31;
    int g = gt >> 5;
    int ngroups = (gridDim.x * blockDim.x) >> 5;
    float b1j = b1[j];
    float b2j = b2[j];
    for (int e = g; e < E; e += ngroups) {
        int row = ei[e];
        int col = ei[E + e];
        row = ((unsigned)row < (unsigned)N) ? row : 0;
        col = ((unsigned)col < (unsigned)N) ? col : 0;
        float dx = pos[row * 3 + 0] - pos[col * 3 + 0];
        float dy = pos[row * 3 + 1] - pos[col * 3 + 1];
        float dz = pos[row * 3 + 2] - pos[col * 3 + 2];
        float dist = sqrtf(fmaf(dx, dx, fmaf(dy, dy, dz * dz)) + 1e-12f);
        float my_rbf = rbf_lane(dist, j & 7);
        float xr[C];
#pragma unroll
        for (int c = 0; c < C; ++c) xr[c] = x[(size_t)col * C + c];
        float h = b1j;
#pragma unroll
        for (int r = 0; r < R; ++r) {
            float s = 0.f;
#pragma unroll
            for (int c = 0; c < C; ++c)
                s = fmaf(xr[c], Ms[r * C * C + c * C + j], s);
            h = fmaf(__shfl(my_rbf, r, 32), s, h);
        }
        float sh = h / (1.f + __expf(-h));
        float v = b2j;
#pragma unroll
        for (int i = 0; i < C; ++i)
            v = fmaf(__shfl(sh, i, 32), W2s[i * C + j], v);
        atomicAdd(&out[(size_t)row * C + j], v);
    }
}

__global__ void k_add_x(const float* __restrict__ x, float* __restrict__ out, int total) {
    int i = blockIdx.x * blockDim.x + threadIdx.x;
    int stride = gridDim.x * blockDim.x;
    for (; i < total; i += stride) out[i] += x[i];
}

extern "C" void kernel_launch(void* const* d_in, const int* in_sizes, int n_in,
                              void* d_out, int out_size, void* d_ws, size_t ws_size,
                              hipStream_t stream) {
    const float* x   = (const float*)d_in[0];
    const float* pos = (const float*)d_in[1];
    const int*   ei  = (const int*)d_in[2];
    const float* Wtp = (const float*)d_in[3];
    const float* W1  = (const float*)d_in[4];
    const float* b1  = (const float*)d_in[5];
    const float* W2  = (const float*)d_in[6];
    const float* b2  = (const float*)d_in[7];
    int N = in_sizes[0] / C;
    int E = in_sizes[2] / 2;

    char* ws = (char*)d_ws;
    size_t mBytes   = (size_t)R * C * C * sizeof(float);              // 32 KB
    size_t zBytes   = (size_t)N * R * C * sizeof(__hip_bfloat16);     // 25.6 MB
    size_t histB    = (size_t)N * sizeof(int);
    size_t rowptrB  = (size_t)(N + 1) * sizeof(int);
    size_t cursorB  = (size_t)N * sizeof(int);
    size_t colB     = (size_t)E * sizeof(int);
    size_t aggBytes = (size_t)N * (C + 1) * sizeof(float);            // tier B
    size_t tierANeed = mBytes + zBytes + histB + rowptrB + cursorB + colB;
    bool tierA = ws_size >= tierANeed;
    bool tierB = !tierA && ws_size >= mBytes + aggBytes;

    if (tierA) {
        float*          M      = (float*)ws;
        __hip_bfloat16* z      = (__hip_bfloat16*)(ws + mBytes);
        int*            hist   = (int*)(ws + mBytes + zBytes);
        int*            rowptr = (int*)(ws + mBytes + zBytes + histB);
        int*            cursor = (int*)(ws + mBytes + zBytes + histB + rowptrB);
        int*            csrcol = (int*)(ws + mBytes + zBytes + histB + rowptrB + cursorB);

        hipMemsetAsync(hist, 0, histB, stream);
        k_prepM<<<(R * C * C + 255) / 256, 256, 0, stream>>>(Wtp, W1, M);
        int npb = 32;
        k_nodeZ<<<(N + npb - 1) / npb, 256, 0, stream>>>(x, M, z, N, npb);
        k_hist<<<(E + 255) / 256, 256, 0, stream>>>(ei, hist, E, N);
        k_scan<<<1, 1024, 0, stream>>>(hist, rowptr, cursor, N, E);
        k_scatter<<<(E + 255) / 256, 256, 0, stream>>>(ei, cursor, csrcol, E, N);
        int blocks = (int)(((size_t)N * 32 + 255) / 256);
        k_edge_csr<<<blocks, 256, 0, stream>>>(rowptr, csrcol, pos, z, x, b1, W2, b2,
                                               (float*)d_out, N);
    } else if (tierB) {
        float* M   = (float*)ws;
        float* agg = (float*)(ws + mBytes);
        float* deg = agg + (size_t)N * C;
        hipMemsetAsync(agg, 0, aggBytes, stream);
        k_prepM<<<(R * C * C + 255) / 256, 256, 0, stream>>>(Wtp, W1, M);
        k_edge_direct<<<2048, 256, 0, stream>>>(ei, pos, x, M, b1, agg, deg, E, N);
        k_final<<<1024, 256, 0, stream>>>(x, agg, deg, W2, b2, (float*)d_out, N);
    } else {
        hipMemsetAsync(d_out, 0, (size_t)N * C * sizeof(float), stream);
        k_edge_full<<<1024, 256, 0, stream>>>(ei, pos, x, Wtp, W1, b1, W2, b2,
                                              (float*)d_out, E, N);
        k_add_x<<<1024, 256, 0, stream>>>(x, (float*)d_out, N * C);
    }
}

// Round 6
// 234.154 us; speedup vs baseline: 1.3174x; 1.3174x over previous
//
#include <hip/hip_runtime.h>
#include <hip/hip_bf16.h>

#define C 32
#define R 8
#define SCAN_G 16384   // 64 blocks x 256 threads

typedef unsigned int u32;
__device__ __forceinline__ float bflo(u32 u) { return __uint_as_float(u << 16); }
__device__ __forceinline__ float bfhi(u32 u) { return __uint_as_float(u & 0xffff0000u); }

// ---- M[r][c][j] = sum_o W_tp[c][r][o] * W1[r*C+o][j]   (f32, 32 KB) ----
__global__ void k_prepM(const float* __restrict__ Wtp, const float* __restrict__ W1,
                        float* __restrict__ M) {
    int idx = blockIdx.x * 256 + threadIdx.x;
    if (idx >= R * C * C) return;
    int r = idx >> 10;
    int c = (idx >> 5) & 31;
    int j = idx & 31;
    float acc = 0.f;
#pragma unroll
    for (int o = 0; o < C; ++o)
        acc = fmaf(Wtp[c * R * C + r * C + o], W1[(r * C + o) * C + j], acc);
    M[idx] = acc;
}

// ---- z[n][j][r] = sum_c x[n][c] * M[r][c][j]  (bf16; r contiguous) ----
__global__ void k_nodeZ(const float* __restrict__ x, const float* __restrict__ M,
                        __hip_bfloat16* __restrict__ z, int N, int npb) {
    int t = threadIdx.x;
    int r = t & 7, j = t >> 3;
    float m[C];
#pragma unroll
    for (int c = 0; c < C; ++c) m[c] = M[r * C * C + c * C + j];
    int n0 = blockIdx.x * npb;
    int n1 = n0 + npb;
    if (n1 > N) n1 = N;
    for (int n = n0; n < n1; ++n) {
        const float* xp = x + (size_t)n * C;
        float acc = 0.f;
#pragma unroll
        for (int c = 0; c < C; ++c) acc = fmaf(xp[c], m[c], acc);
        z[(size_t)n * (R * C) + t] = __float2bfloat16(acc);
    }
}

// rbf: centers = linspace(0,5,8), width = 5/7, scaling = 1/sqrt(2pi)
__device__ __forceinline__ float rbf_lane(float dist, int r) {
    float t = (dist - 0.71428573f * (float)r) * 1.3999999f;
    return 0.3989423f * __expf(-0.5f * t * t);
}

// ---- CSR build ----
__global__ void k_hist(const int* __restrict__ ei, int* __restrict__ hist, int E, int N) {
    int i = blockIdx.x * blockDim.x + threadIdx.x;
    int stride = gridDim.x * blockDim.x;
    for (; i < E; i += stride) {
        int r = ei[i];
        r = ((unsigned)r < (unsigned)N) ? r : 0;
        atomicAdd(&hist[r], 1);
    }
}

// scan1: thread t sums hist[t*CH .. ) -> tsum[t]   (grid 64x256 = SCAN_G)
__global__ void k_scan1(const int* __restrict__ hist, int* __restrict__ tsum,
                        int N, int CH) {
    int t = blockIdx.x * blockDim.x + threadIdx.x;
    int a0 = t * CH;
    int a1 = a0 + CH; if (a1 > N) a1 = N;
    int s = 0;
    for (int a = a0; a < a1; ++a) s += hist[a];
    tsum[t] = s;
}

// scan2: exclusive-scan tsum[0..SCAN_G) in place; 1 block x 1024, 16 per thread
__global__ void k_scan2(int* __restrict__ tsum) {
    __shared__ int s[1024];
    int t = threadIdx.x;
    int vals[16];
    int sum = 0;
#pragma unroll
    for (int i = 0; i < 16; ++i) { vals[i] = tsum[t * 16 + i]; sum += vals[i]; }
    s[t] = sum;
    __syncthreads();
    for (int off = 1; off < 1024; off <<= 1) {
        int v = (t >= off) ? s[t - off] : 0;
        __syncthreads();
        s[t] += v;
        __syncthreads();
    }
    int base = (t == 0) ? 0 : s[t - 1];
#pragma unroll
    for (int i = 0; i < 16; ++i) { tsum[t * 16 + i] = base; base += vals[i]; }
}

// scan3: thread t writes rowptr/cursor for its chunk using tsum[t] base
__global__ void k_scan3(const int* __restrict__ hist, const int* __restrict__ tsum,
                        int* __restrict__ rowptr, int* __restrict__ cursor,
                        int N, int CH, int E) {
    int t = blockIdx.x * blockDim.x + threadIdx.x;
    int a0 = t * CH;
    int a1 = a0 + CH; if (a1 > N) a1 = N;
    int run = tsum[t];
    for (int a = a0; a < a1; ++a) {
        rowptr[a] = run;
        cursor[a] = run;
        run += hist[a];
    }
    if (t == 0) rowptr[N] = E;
}

__global__ void k_scatter(const int* __restrict__ ei, int* __restrict__ cursor,
                          int* __restrict__ csr_col, int E, int N) {
    int i = blockIdx.x * blockDim.x + threadIdx.x;
    int stride = gridDim.x * blockDim.x;
    for (; i < E; i += stride) {
        int r = ei[i];
        int cc = ei[E + i];
        r  = ((unsigned)r  < (unsigned)N) ? r  : 0;
        cc = ((unsigned)cc < (unsigned)N) ? cc : 0;
        int p = atomicAdd(&cursor[r], 1);
        csr_col[p] = cc;
    }
}

// ---- per-row edge kernel: 32 lanes = one row; cols staged in regs, 4-wide ILP ----
__device__ __forceinline__ float edge_h(float px, float py, float pz,
                                        const float* __restrict__ pos, int c,
                                        const __hip_bfloat16* __restrict__ z,
                                        int j, int rr, float b1j) {
    float dx = px - pos[c * 3 + 0];
    float dy = py - pos[c * 3 + 1];
    float dz = pz - pos[c * 3 + 2];
    float dist = sqrtf(fmaf(dx, dx, fmaf(dy, dy, dz * dz)) + 1e-12f);
    float ra = rbf_lane(dist, rr);
    uint4 v = ((const uint4*)(z + (size_t)c * (R * C)))[j];
    float h = b1j;
    h = fmaf(__shfl(ra, 0, 32), bflo(v.x), h);
    h = fmaf(__shfl(ra, 1, 32), bfhi(v.x), h);
    h = fmaf(__shfl(ra, 2, 32), bflo(v.y), h);
    h = fmaf(__shfl(ra, 3, 32), bfhi(v.y), h);
    h = fmaf(__shfl(ra, 4, 32), bflo(v.z), h);
    h = fmaf(__shfl(ra, 5, 32), bfhi(v.z), h);
    h = fmaf(__shfl(ra, 6, 32), bflo(v.w), h);
    h = fmaf(__shfl(ra, 7, 32), bfhi(v.w), h);
    return h;
}

__global__ void k_edge_csr(const int* __restrict__ rowptr, const int* __restrict__ csr_col,
                           const float* __restrict__ pos, const __hip_bfloat16* __restrict__ z,
                           const float* __restrict__ x, const float* __restrict__ b1,
                           const float* __restrict__ W2, const float* __restrict__ b2,
                           float* __restrict__ out, int N) {
    __shared__ float W2s[C * C];
    for (int i = threadIdx.x; i < C * C; i += blockDim.x) W2s[i] = W2[i];
    __syncthreads();
    int gt = blockIdx.x * blockDim.x + threadIdx.x;
    int j = gt & 31;
    int n = gt >> 5;
    if (n >= N) return;
    int p0 = rowptr[n];
    int p1 = rowptr[n + 1];
    float px = pos[n * 3 + 0], py = pos[n * 3 + 1], pz = pos[n * 3 + 2];
    float b1j = b1[j];
    int rr = j & 7;
    float acc = 0.f;
    for (int base = p0; base < p1; base += 32) {
        int cnt = p1 - base; if (cnt > 32) cnt = 32;
        int myc = csr_col[base + ((j < cnt) ? j : (cnt - 1))];  // one coalesced load
        for (int k = 0; k < cnt; k += 4) {
            int k1 = (k + 1 < cnt) ? k + 1 : cnt - 1;
            int k2 = (k + 2 < cnt) ? k + 2 : cnt - 1;
            int k3 = (k + 3 < cnt) ? k + 3 : cnt - 1;
            int c0 = __shfl(myc, k, 32);
            int c1 = __shfl(myc, k1, 32);
            int c2 = __shfl(myc, k2, 32);
            int c3 = __shfl(myc, k3, 32);
            float m1 = (k + 1 < cnt) ? 1.f : 0.f;
            float m2 = (k + 2 < cnt) ? 1.f : 0.f;
            float m3 = (k + 3 < cnt) ? 1.f : 0.f;
            float h0 = edge_h(px, py, pz, pos, c0, z, j, rr, b1j);
            float h1 = edge_h(px, py, pz, pos, c1, z, j, rr, b1j);
            float h2 = edge_h(px, py, pz, pos, c2, z, j, rr, b1j);
            float h3 = edge_h(px, py, pz, pos, c3, z, j, rr, b1j);
            float s0 = h0 / (1.f + __expf(-h0));
            float s1 = h1 / (1.f + __expf(-h1));
            float s2 = h2 / (1.f + __expf(-h2));
            float s3 = h3 / (1.f + __expf(-h3));
            acc += s0;
            acc = fmaf(m1, s1, acc);
            acc = fmaf(m2, s2, acc);
            acc = fmaf(m3, s3, acc);
        }
    }
    // epilogue: out[n][j] = x[n][j] + sum_i acc_i * W2[i][j] + deg * b2[j]
    float v = fmaf((float)(p1 - p0), b2[j], x[(size_t)n * C + j]);
#pragma unroll
    for (int i = 0; i < C; ++i)
        v = fmaf(__shfl(acc, i, 32), W2s[i * C + j], v);
    out[(size_t)n * C + j] = v;
}

// ---- Tier B kernels (proven fallback) ----
__global__ void k_edge_direct(const int* __restrict__ ei, const float* __restrict__ pos,
                              const float* __restrict__ x, const float* __restrict__ M,
                              const float* __restrict__ b1,
                              float* __restrict__ agg, float* __restrict__ deg,
                              int E, int N) {
    __shared__ float Ms[R * C * C];
    for (int i = threadIdx.x; i < R * C * C; i += blockDim.x) Ms[i] = M[i];
    __syncthreads();
    int gt = blockIdx.x * blockDim.x + threadIdx.x;
    int j = gt & 31;
    int g = gt >> 5;
    int ngroups = (gridDim.x * blockDim.x) >> 5;
    float b1j = b1[j];
    for (int e = g; e < E; e += ngroups) {
        int row = ei[e];
        int col = ei[E + e];
        row = ((unsigned)row < (unsigned)N) ? row : 0;
        col = ((unsigned)col < (unsigned)N) ? col : 0;
        float dx = pos[row * 3 + 0] - pos[col * 3 + 0];
        float dy = pos[row * 3 + 1] - pos[col * 3 + 1];
        float dz = pos[row * 3 + 2] - pos[col * 3 + 2];
        float dist = sqrtf(fmaf(dx, dx, fmaf(dy, dy, dz * dz)) + 1e-12f);
        float my_rbf = rbf_lane(dist, j & 7);
        float xr[C];
#pragma unroll
        for (int c = 0; c < C; ++c) xr[c] = x[(size_t)col * C + c];
        float h = b1j;
#pragma unroll
        for (int r = 0; r < R; ++r) {
            float s = 0.f;
#pragma unroll
            for (int c = 0; c < C; ++c)
                s = fmaf(xr[c], Ms[r * C * C + c * C + j], s);
            h = fmaf(__shfl(my_rbf, r, 32), s, h);
        }
        float sh = h / (1.f + __expf(-h));
        atomicAdd(&agg[(size_t)row * C + j], sh);
        if (j == 0) atomicAdd(&deg[row], 1.f);
    }
}

__global__ void k_final(const float* __restrict__ x, const float* __restrict__ agg,
                        const float* __restrict__ deg, const float* __restrict__ W2,
                        const float* __restrict__ b2, float* __restrict__ out,
                        int N) {
    int t = threadIdx.x;
    int j = t & 31;
    float w2[C];
#pragma unroll
    for (int i = 0; i < C; ++i) w2[i] = W2[i * C + j];
    float b2j = b2[j];
    int g = (blockIdx.x * blockDim.x + t) >> 5;
    int ngroups = (gridDim.x * blockDim.x) >> 5;
    for (int n = g; n < N; n += ngroups) {
        const float* ap = agg + (size_t)n * C;
        float acc = 0.f;
#pragma unroll
        for (int i = 0; i < C; ++i) acc = fmaf(ap[i], w2[i], acc);
        out[(size_t)n * C + j] = x[(size_t)n * C + j] + acc + deg[n] * b2j;
    }
}

// ---- Tier C (no usable ws) ----
__global__ void k_edge_full(const int* __restrict__ ei, const float* __restrict__ pos,
                            const float* __restrict__ x,
                            const float* __restrict__ Wtp, const float* __restrict__ W1,
                            const float* __restrict__ b1,
                            const float* __restrict__ W2, const float* __restrict__ b2,
                            float* __restrict__ out, int E, int N) {
    __shared__ float Ms[R * C * C];
    __shared__ float W2s[C * C];
    for (int idx = threadIdx.x; idx < R * C * C; idx += blockDim.x) {
        int r = idx >> 10, c = (idx >> 5) & 31, jj = idx & 31;
        float acc = 0.f;
#pragma unroll
        for (int o = 0; o < C; ++o)
            acc = fmaf(Wtp[c * R * C + r * C + o], W1[(r * C + o) * C + jj], acc);
        Ms[idx] = acc;
    }
    for (int idx = threadIdx.x; idx < C * C; idx += blockDim.x) W2s[idx] = W2[idx];
    __syncthreads();
    int gt = blockIdx.x * blockDim.x + threadIdx.x;
    int j = gt & 31;
    int g = gt >> 5;
    int ngroups = (gridDim.x * blockDim.x) >> 5;
    float b1j = b1[j];
    float b2j = b2[j];
    for (int e = g; e < E; e += ngroups) {
        int row = ei[e];
        int col = ei[E + e];
        row = ((unsigned)row < (unsigned)N) ? row : 0;
        col = ((unsigned)col < (unsigned)N) ? col : 0;
        float dx = pos[row * 3 + 0] - pos[col * 3 + 0];
        float dy = pos[row * 3 + 1] - pos[col * 3 + 1];
        float dz = pos[row * 3 + 2] - pos[col * 3 + 2];
        float dist = sqrtf(fmaf(dx, dx, fmaf(dy, dy, dz * dz)) + 1e-12f);
        float my_rbf = rbf_lane(dist, j & 7);
        float xr[C];
#pragma unroll
        for (int c = 0; c < C; ++c) xr[c] = x[(size_t)col * C + c];
        float h = b1j;
#pragma unroll
        for (int r = 0; r < R; ++r) {
            float s = 0.f;
#pragma unroll
            for (int c = 0; c < C; ++c)
                s = fmaf(xr[c], Ms[r * C * C + c * C + j], s);
            h = fmaf(__shfl(my_rbf, r, 32), s, h);
        }
        float sh = h / (1.f + __expf(-h));
        float v = b2j;
#pragma unroll
        for (int i = 0; i < C; ++i)
            v = fmaf(__shfl(sh, i, 32), W2s[i * C + j], v);
        atomicAdd(&out[(size_t)row * C + j], v);
    }
}

__global__ void k_add_x(const float* __restrict__ x, float* __restrict__ out, int total) {
    int i = blockIdx.x * blockDim.x + threadIdx.x;
    int stride = gridDim.x * blockDim.x;
    for (; i < total; i += stride) out[i] += x[i];
}

extern "C" void kernel_launch(void* const* d_in, const int* in_sizes, int n_in,
                              void* d_out, int out_size, void* d_ws, size_t ws_size,
                              hipStream_t stream) {
    const float* x   = (const float*)d_in[0];
    const float* pos = (const float*)d_in[1];
    const int*   ei  = (const int*)d_in[2];
    const float* Wtp = (const float*)d_in[3];
    const float* W1  = (const float*)d_in[4];
    const float* b1  = (const float*)d_in[5];
    const float* W2  = (const float*)d_in[6];
    const float* b2  = (const float*)d_in[7];
    int N = in_sizes[0] / C;
    int E = in_sizes[2] / 2;

    char* ws = (char*)d_ws;
    size_t mBytes   = (size_t)R * C * C * sizeof(float);              // 32 KB
    size_t zBytes   = (size_t)N * R * C * sizeof(__hip_bfloat16);     // 25.6 MB
    size_t histB    = (size_t)N * sizeof(int);
    size_t rowptrB  = (size_t)(N + 1) * sizeof(int);
    size_t cursorB  = (size_t)N * sizeof(int);
    size_t colB     = (size_t)E * sizeof(int);
    size_t tsumB    = (size_t)SCAN_G * sizeof(int);                   // 64 KB
    size_t aggBytes = (size_t)N * (C + 1) * sizeof(float);            // tier B
    size_t tierANeed = mBytes + zBytes + histB + rowptrB + cursorB + colB + tsumB;
    bool tierA = ws_size >= tierANeed;
    bool tierB = !tierA && ws_size >= mBytes + aggBytes;

    if (tierA) {
        float*          M      = (float*)ws;
        __hip_bfloat16* z      = (__hip_bfloat16*)(ws + mBytes);
        int*            hist   = (int*)(ws + mBytes + zBytes);
        int*            rowptr = (int*)(ws + mBytes + zBytes + histB);
        int*            cursor = (int*)(ws + mBytes + zBytes + histB + rowptrB);
        int*            csrcol = (int*)(ws + mBytes + zBytes + histB + rowptrB + cursorB);
        int*            tsum   = (int*)(ws + mBytes + zBytes + histB + rowptrB + cursorB + colB);

        int CH = (N + SCAN_G - 1) / SCAN_G;
        hipMemsetAsync(hist, 0, histB, stream);
        k_prepM<<<(R * C * C + 255) / 256, 256, 0, stream>>>(Wtp, W1, M);
        int npb = 32;
        k_nodeZ<<<(N + npb - 1) / npb, 256, 0, stream>>>(x, M, z, N, npb);
        k_hist<<<(E + 255) / 256, 256, 0, stream>>>(ei, hist, E, N);
        k_scan1<<<SCAN_G / 256, 256, 0, stream>>>(hist, tsum, N, CH);
        k_scan2<<<1, 1024, 0, stream>>>(tsum);
        k_scan3<<<SCAN_G / 256, 256, 0, stream>>>(hist, tsum, rowptr, cursor, N, CH, E);
        k_scatter<<<(E + 255) / 256, 256, 0, stream>>>(ei, cursor, csrcol, E, N);
        int blocks = (int)(((size_t)N * 32 + 255) / 256);
        k_edge_csr<<<blocks, 256, 0, stream>>>(rowptr, csrcol, pos, z, x, b1, W2, b2,
                                               (float*)d_out, N);
    } else if (tierB) {
        float* M   = (float*)ws;
        float* agg = (float*)(ws + mBytes);
        float* deg = agg + (size_t)N * C;
        hipMemsetAsync(agg, 0, aggBytes, stream);
        k_prepM<<<(R * C * C + 255) / 256, 256, 0, stream>>>(Wtp, W1, M);
        k_edge_direct<<<2048, 256, 0, stream>>>(ei, pos, x, M, b1, agg, deg, E, N);
        k_final<<<1024, 256, 0, stream>>>(x, agg, deg, W2, b2, (float*)d_out, N);
    } else {
        hipMemsetAsync(d_out, 0, (size_t)N * C * sizeof(float), stream);
        k_edge_full<<<1024, 256, 0, stream>>>(ei, pos, x, Wtp, W1, b1, W2, b2,
                                              (float*)d_out, E, N);
        k_add_x<<<1024, 256, 0, stream>>>(x, (float*)d_out, N * C);
    }
}

// Round 7
// 213.385 us; speedup vs baseline: 1.4456x; 1.0973x over previous
//
#include <hip/hip_runtime.h>
#include <hip/hip_bf16.h>

#define C 32
#define R 8
#define SCAN_G 16384   // 64 blocks x 256 threads
#define NPB 32         // nodes per block in k_nodeZ

typedef unsigned int u32;
__device__ __forceinline__ float bflo(u32 u) { return __uint_as_float(u << 16); }
__device__ __forceinline__ float bfhi(u32 u) { return __uint_as_float(u & 0xffff0000u); }
// f32 -> bf16 bits with round-to-nearest-even
__device__ __forceinline__ u32 f2bf_bits(float f) {
    u32 u = __float_as_uint(f);
    u32 lsb = (u >> 16) & 1u;
    return (u + 0x7fffu + lsb) >> 16;
}

// ---- M[r][c][j] = sum_o W_tp[c][r][o] * W1[r*C+o][j]   (f32, 32 KB) ----
__global__ void k_prepM(const float* __restrict__ Wtp, const float* __restrict__ W1,
                        float* __restrict__ M) {
    int idx = blockIdx.x * 256 + threadIdx.x;
    if (idx >= R * C * C) return;
    int r = idx >> 10;
    int c = (idx >> 5) & 31;
    int j = idx & 31;
    float acc = 0.f;
#pragma unroll
    for (int o = 0; o < C; ++o)
        acc = fmaf(Wtp[c * R * C + r * C + o], W1[(r * C + o) * C + j], acc);
    M[idx] = acc;
}

// ---- z[n][j][r] = sum_c x[n][c] * M[r][c][j]  (bf16; r contiguous), x via LDS ----
__global__ void k_nodeZ(const float* __restrict__ x, const float* __restrict__ M,
                        __hip_bfloat16* __restrict__ z, int N) {
    __shared__ float xs[NPB * C];
    int t = threadIdx.x;
    int n0 = blockIdx.x * NPB;
    // cooperative coalesced load of x[n0 .. n0+NPB) (guard tail)
    for (int i = t * 4; i < NPB * C; i += 256 * 4) {
        size_t gbase = (size_t)n0 * C + i;
        float4 v = make_float4(0.f, 0.f, 0.f, 0.f);
        if (gbase + 3 < (size_t)N * C) v = *(const float4*)(x + gbase);
        *(float4*)(xs + i) = v;
    }
    __syncthreads();
    int r = t & 7, j = t >> 3;
    float m[C];
#pragma unroll
    for (int c = 0; c < C; ++c) m[c] = M[r * C * C + c * C + j];
    int nmax = N - n0; if (nmax > NPB) nmax = NPB;
    for (int nn = 0; nn < nmax; ++nn) {
        const float* xp = xs + nn * C;
        float acc = 0.f;
#pragma unroll
        for (int c = 0; c < C; ++c) acc = fmaf(xp[c], m[c], acc);
        z[(size_t)(n0 + nn) * (R * C) + t] = __float2bfloat16(acc);
    }
}

// ---- CSR build ----
__global__ void k_hist(const int* __restrict__ ei, int* __restrict__ hist, int E, int N) {
    int i = blockIdx.x * blockDim.x + threadIdx.x;
    int stride = gridDim.x * blockDim.x;
    for (; i < E; i += stride) {
        int r = ei[i];
        r = ((unsigned)r < (unsigned)N) ? r : 0;
        atomicAdd(&hist[r], 1);
    }
}

__global__ void k_scan1(const int* __restrict__ hist, int* __restrict__ tsum,
                        int N, int CH) {
    int t = blockIdx.x * blockDim.x + threadIdx.x;
    int a0 = t * CH;
    int a1 = a0 + CH; if (a1 > N) a1 = N;
    int s = 0;
    for (int a = a0; a < a1; ++a) s += hist[a];
    tsum[t] = s;
}

__global__ void k_scan2(int* __restrict__ tsum) {
    __shared__ int s[1024];
    int t = threadIdx.x;
    int vals[16];
    int sum = 0;
#pragma unroll
    for (int i = 0; i < 16; ++i) { vals[i] = tsum[t * 16 + i]; sum += vals[i]; }
    s[t] = sum;
    __syncthreads();
    for (int off = 1; off < 1024; off <<= 1) {
        int v = (t >= off) ? s[t - off] : 0;
        __syncthreads();
        s[t] += v;
        __syncthreads();
    }
    int base = (t == 0) ? 0 : s[t - 1];
#pragma unroll
    for (int i = 0; i < 16; ++i) { tsum[t * 16 + i] = base; base += vals[i]; }
}

__global__ void k_scan3(const int* __restrict__ hist, const int* __restrict__ tsum,
                        int* __restrict__ rowptr, int* __restrict__ cursor,
                        int N, int CH, int E) {
    int t = blockIdx.x * blockDim.x + threadIdx.x;
    int a0 = t * CH;
    int a1 = a0 + CH; if (a1 > N) a1 = N;
    int run = tsum[t];
    for (int a = a0; a < a1; ++a) {
        rowptr[a] = run;
        cursor[a] = run;
        run += hist[a];
    }
    if (t == 0) rowptr[N] = E;
}

// ---- scatter + per-edge geometry: record[p] = {col, pad, rbf01, rbf23, rbf45, rbf67, 0, 0}
__global__ void k_scatter_rbf(const int* __restrict__ ei, const float* __restrict__ pos,
                              int* __restrict__ cursor, uint4* __restrict__ recs,
                              int E, int N) {
    int i = blockIdx.x * blockDim.x + threadIdx.x;
    int stride = gridDim.x * blockDim.x;
    for (; i < E; i += stride) {
        int r = ei[i];
        int c = ei[E + i];
        r = ((unsigned)r < (unsigned)N) ? r : 0;
        c = ((unsigned)c < (unsigned)N) ? c : 0;
        float dx = pos[r * 3 + 0] - pos[c * 3 + 0];
        float dy = pos[r * 3 + 1] - pos[c * 3 + 1];
        float dz = pos[r * 3 + 2] - pos[c * 3 + 2];
        float dist = sqrtf(fmaf(dx, dx, fmaf(dy, dy, dz * dz)) + 1e-12f);
        // centers = linspace(0,5,8), width = 5/7, scaling = 1/sqrt(2pi)
        u32 rb[R];
#pragma unroll
        for (int rr = 0; rr < R; ++rr) {
            float t = (dist - 0.71428573f * (float)rr) * 1.3999999f;
            rb[rr] = f2bf_bits(0.3989423f * __expf(-0.5f * t * t));
        }
        int p = atomicAdd(&cursor[r], 1);
        uint4 w0, w1;
        w0.x = (u32)c;
        w0.y = 0u;
        w0.z = rb[0] | (rb[1] << 16);
        w0.w = rb[2] | (rb[3] << 16);
        w1.x = rb[4] | (rb[5] << 16);
        w1.y = rb[6] | (rb[7] << 16);
        w1.z = 0u; w1.w = 0u;
        recs[2 * p + 0] = w0;
        recs[2 * p + 1] = w1;
    }
}

// h = b1 + sum_r rbf[r] * z[col][j][r]
__device__ __forceinline__ float edge_dot(uint4 r0, uint4 r1, uint4 zv, float b1j) {
    float h = b1j;
    h = fmaf(bflo(r0.z), bflo(zv.x), h);
    h = fmaf(bfhi(r0.z), bfhi(zv.x), h);
    h = fmaf(bflo(r0.w), bflo(zv.y), h);
    h = fmaf(bfhi(r0.w), bfhi(zv.y), h);
    h = fmaf(bflo(r1.x), bflo(zv.z), h);
    h = fmaf(bfhi(r1.x), bfhi(zv.z), h);
    h = fmaf(bflo(r1.y), bflo(zv.w), h);
    h = fmaf(bfhi(r1.y), bfhi(zv.w), h);
    return h;
}
__device__ __forceinline__ float silu_f(float h) {
    return h * __builtin_amdgcn_rcpf(1.f + __expf(-h));
}

// ---- per-row edge kernel: 32 lanes = one row; records pre-baked; fused epilogue ----
__global__ void k_edge_csr(const int* __restrict__ rowptr, const uint4* __restrict__ recs,
                           const __hip_bfloat16* __restrict__ z,
                           const float* __restrict__ x, const float* __restrict__ b1,
                           const float* __restrict__ W2, const float* __restrict__ b2,
                           float* __restrict__ out, int N) {
    __shared__ float W2s[C * C];
    for (int i = threadIdx.x; i < C * C; i += blockDim.x) W2s[i] = W2[i];
    __syncthreads();
    int gt = blockIdx.x * blockDim.x + threadIdx.x;
    int j = gt & 31;
    int n = gt >> 5;
    if (n >= N) return;
    int p0 = rowptr[n];
    int p1 = rowptr[n + 1];
    float b1j = b1[j];
    float acc = 0.f;
    int p = p0;
    for (; p + 4 <= p1; p += 4) {
        uint4 a0 = recs[2 * p + 0], a1 = recs[2 * p + 1];
        uint4 b0 = recs[2 * p + 2], b1r = recs[2 * p + 3];
        uint4 c0 = recs[2 * p + 4], c1 = recs[2 * p + 5];
        uint4 d0 = recs[2 * p + 6], d1 = recs[2 * p + 7];
        uint4 za = ((const uint4*)(z + (size_t)a0.x * (R * C)))[j];
        uint4 zb = ((const uint4*)(z + (size_t)b0.x * (R * C)))[j];
        uint4 zc = ((const uint4*)(z + (size_t)c0.x * (R * C)))[j];
        uint4 zd = ((const uint4*)(z + (size_t)d0.x * (R * C)))[j];
        float ha = edge_dot(a0, a1, za, b1j);
        float hb = edge_dot(b0, b1r, zb, b1j);
        float hc = edge_dot(c0, c1, zc, b1j);
        float hd = edge_dot(d0, d1, zd, b1j);
        acc += silu_f(ha) + silu_f(hb) + silu_f(hc) + silu_f(hd);
    }
    for (; p < p1; ++p) {
        uint4 a0 = recs[2 * p + 0], a1 = recs[2 * p + 1];
        uint4 za = ((const uint4*)(z + (size_t)a0.x * (R * C)))[j];
        acc += silu_f(edge_dot(a0, a1, za, b1j));
    }
    // epilogue: out[n][j] = x[n][j] + sum_i acc_i * W2[i][j] + deg * b2[j]
    float v = fmaf((float)(p1 - p0), b2[j], x[(size_t)n * C + j]);
#pragma unroll
    for (int i = 0; i < C; ++i)
        v = fmaf(__shfl(acc, i, 32), W2s[i * C + j], v);
    out[(size_t)n * C + j] = v;
}

// rbf for fallback tiers
__device__ __forceinline__ float rbf_lane(float dist, int r) {
    float t = (dist - 0.71428573f * (float)r) * 1.3999999f;
    return 0.3989423f * __expf(-0.5f * t * t);
}

// ---- Tier B kernels (proven fallback) ----
__global__ void k_edge_direct(const int* __restrict__ ei, const float* __restrict__ pos,
                              const float* __restrict__ x, const float* __restrict__ M,
                              const float* __restrict__ b1,
                              float* __restrict__ agg, float* __restrict__ deg,
                              int E, int N) {
    __shared__ float Ms[R * C * C];
    for (int i = threadIdx.x; i < R * C * C; i += blockDim.x) Ms[i] = M[i];
    __syncthreads();
    int gt = blockIdx.x * blockDim.x + threadIdx.x;
    int j = gt & 31;
    int g = gt >> 5;
    int ngroups = (gridDim.x * blockDim.x) >> 5;
    float b1j = b1[j];
    for (int e = g; e < E; e += ngroups) {
        int row = ei[e];
        int col = ei[E + e];
        row = ((unsigned)row < (unsigned)N) ? row : 0;
        col = ((unsigned)col < (unsigned)N) ? col : 0;
        float dx = pos[row * 3 + 0] - pos[col * 3 + 0];
        float dy = pos[row * 3 + 1] - pos[col * 3 + 1];
        float dz = pos[row * 3 + 2] - pos[col * 3 + 2];
        float dist = sqrtf(fmaf(dx, dx, fmaf(dy, dy, dz * dz)) + 1e-12f);
        float my_rbf = rbf_lane(dist, j & 7);
        float xr[C];
#pragma unroll
        for (int c = 0; c < C; ++c) xr[c] = x[(size_t)col * C + c];
        float h = b1j;
#pragma unroll
        for (int r = 0; r < R; ++r) {
            float s = 0.f;
#pragma unroll
            for (int c = 0; c < C; ++c)
                s = fmaf(xr[c], Ms[r * C * C + c * C + j], s);
            h = fmaf(__shfl(my_rbf, r, 32), s, h);
        }
        float sh = h / (1.f + __expf(-h));
        atomicAdd(&agg[(size_t)row * C + j], sh);
        if (j == 0) atomicAdd(&deg[row], 1.f);
    }
}

__global__ void k_final(const float* __restrict__ x, const float* __restrict__ agg,
                        const float* __restrict__ deg, const float* __restrict__ W2,
                        const float* __restrict__ b2, float* __restrict__ out,
                        int N) {
    int t = threadIdx.x;
    int j = t & 31;
    float w2[C];
#pragma unroll
    for (int i = 0; i < C; ++i) w2[i] = W2[i * C + j];
    float b2j = b2[j];
    int g = (blockIdx.x * blockDim.x + t) >> 5;
    int ngroups = (gridDim.x * blockDim.x) >> 5;
    for (int n = g; n < N; n += ngroups) {
        const float* ap = agg + (size_t)n * C;
        float acc = 0.f;
#pragma unroll
        for (int i = 0; i < C; ++i) acc = fmaf(ap[i], w2[i], acc);
        out[(size_t)n * C + j] = x[(size_t)n * C + j] + acc + deg[n] * b2j;
    }
}

// ---- Tier C (no usable ws) ----
__global__ void k_edge_full(const int* __restrict__ ei, const float* __restrict__ pos,
                            const float* __restrict__ x,
                            const float* __restrict__ Wtp, const float* __restrict__ W1,
                            const float* __restrict__ b1,
                            const float* __restrict__ W2, const float* __restrict__ b2,
                            float* __restrict__ out, int E, int N) {
    __shared__ float Ms[R * C * C];
    __shared__ float W2s[C * C];
    for (int idx = threadIdx.x; idx < R * C * C; idx += blockDim.x) {
        int r = idx >> 10, c = (idx >> 5) & 31, jj = idx & 31;
        float acc = 0.f;
#pragma unroll
        for (int o = 0; o < C; ++o)
            acc = fmaf(Wtp[c * R * C + r * C + o], W1[(r * C + o) * C + jj], acc);
        Ms[idx] = acc;
    }
    for (int idx = threadIdx.x; idx < C * C; idx += blockDim.x) W2s[idx] = W2[idx];
    __syncthreads();
    int gt = blockIdx.x * blockDim.x + threadIdx.x;
    int j = gt & 31;
    int g = gt >> 5;
    int ngroups = (gridDim.x * blockDim.x) >> 5;
    float b1j = b1[j];
    float b2j = b2[j];
    for (int e = g; e < E; e += ngroups) {
        int row = ei[e];
        int col = ei[E + e];
        row = ((unsigned)row < (unsigned)N) ? row : 0;
        col = ((unsigned)col < (unsigned)N) ? col : 0;
        float dx = pos[row * 3 + 0] - pos[col * 3 + 0];
        float dy = pos[row * 3 + 1] - pos[col * 3 + 1];
        float dz = pos[row * 3 + 2] - pos[col * 3 + 2];
        float dist = sqrtf(fmaf(dx, dx, fmaf(dy, dy, dz * dz)) + 1e-12f);
        float my_rbf = rbf_lane(dist, j & 7);
        float xr[C];
#pragma unroll
        for (int c = 0; c < C; ++c) xr[c] = x[(size_t)col * C + c];
        float h = b1j;
#pragma unroll
        for (int r = 0; r < R; ++r) {
            float s = 0.f;
#pragma unroll
            for (int c = 0; c < C; ++c)
                s = fmaf(xr[c], Ms[r * C * C + c * C + j], s);
            h = fmaf(__shfl(my_rbf, r, 32), s, h);
        }
        float sh = h / (1.f + __expf(-h));
        float v = b2j;
#pragma unroll
        for (int i = 0; i < C; ++i)
            v = fmaf(__shfl(sh, i, 32), W2s[i * C + j], v);
        atomicAdd(&out[(size_t)row * C + j], v);
    }
}

__global__ void k_add_x(const float* __restrict__ x, float* __restrict__ out, int total) {
    int i = blockIdx.x * blockDim.x + threadIdx.x;
    int stride = gridDim.x * blockDim.x;
    for (; i < total; i += stride) out[i] += x[i];
}

extern "C" void kernel_launch(void* const* d_in, const int* in_sizes, int n_in,
                              void* d_out, int out_size, void* d_ws, size_t ws_size,
                              hipStream_t stream) {
    const float* x   = (const float*)d_in[0];
    const float* pos = (const float*)d_in[1];
    const int*   ei  = (const int*)d_in[2];
    const float* Wtp = (const float*)d_in[3];
    const float* W1  = (const float*)d_in[4];
    const float* b1  = (const float*)d_in[5];
    const float* W2  = (const float*)d_in[6];
    const float* b2  = (const float*)d_in[7];
    int N = in_sizes[0] / C;
    int E = in_sizes[2] / 2;

    char* ws = (char*)d_ws;
    size_t mBytes   = (size_t)R * C * C * sizeof(float);              // 32 KB
    size_t zBytes   = (size_t)N * R * C * sizeof(__hip_bfloat16);     // 25.6 MB
    size_t histB    = (size_t)N * sizeof(int);
    size_t rowptrB  = (size_t)(N + 1) * sizeof(int);
    size_t cursorB  = (size_t)N * sizeof(int);
    size_t recsB    = (size_t)E * 32;                                 // 25.6 MB
    size_t tsumB    = (size_t)SCAN_G * sizeof(int);                   // 64 KB
    size_t aggBytes = (size_t)N * (C + 1) * sizeof(float);            // tier B
    size_t tierANeed = mBytes + zBytes + histB + rowptrB + cursorB + recsB + tsumB;
    bool tierA = ws_size >= tierANeed;
    bool tierB = !tierA && ws_size >= mBytes + aggBytes;

    if (tierA) {
        size_t off = 0;
        float*          M      = (float*)(ws + off); off += mBytes;
        __hip_bfloat16* z      = (__hip_bfloat16*)(ws + off); off += zBytes;
        int*            hist   = (int*)(ws + off); off += histB;
        int*            rowptr = (int*)(ws + off); off += rowptrB;
        int*            cursor = (int*)(ws + off); off += cursorB;
        uint4*          recs   = (uint4*)(ws + off); off += recsB;
        int*            tsum   = (int*)(ws + off);

        int CH = (N + SCAN_G - 1) / SCAN_G;
        hipMemsetAsync(hist, 0, histB, stream);
        k_prepM<<<(R * C * C + 255) / 256, 256, 0, stream>>>(Wtp, W1, M);
        k_nodeZ<<<(N + NPB - 1) / NPB, 256, 0, stream>>>(x, M, z, N);
        k_hist<<<(E + 255) / 256, 256, 0, stream>>>(ei, hist, E, N);
        k_scan1<<<SCAN_G / 256, 256, 0, stream>>>(hist, tsum, N, CH);
        k_scan2<<<1, 1024, 0, stream>>>(tsum);
        k_scan3<<<SCAN_G / 256, 256, 0, stream>>>(hist, tsum, rowptr, cursor, N, CH, E);
        k_scatter_rbf<<<(E + 255) / 256, 256, 0, stream>>>(ei, pos, cursor, recs, E, N);
        int blocks = (int)(((size_t)N * 32 + 255) / 256);
        k_edge_csr<<<blocks, 256, 0, stream>>>(rowptr, recs, z, x, b1, W2, b2,
                                               (float*)d_out, N);
    } else if (tierB) {
        float* M   = (float*)ws;
        float* agg = (float*)(ws + mBytes);
        float* deg = agg + (size_t)N * C;
        hipMemsetAsync(agg, 0, aggBytes, stream);
        k_prepM<<<(R * C * C + 255) / 256, 256, 0, stream>>>(Wtp, W1, M);
        k_edge_direct<<<2048, 256, 0, stream>>>(ei, pos, x, M, b1, agg, deg, E, N);
        k_final<<<1024, 256, 0, stream>>>(x, agg, deg, W2, b2, (float*)d_out, N);
    } else {
        hipMemsetAsync(d_out, 0, (size_t)N * C * sizeof(float), stream);
        k_edge_full<<<1024, 256, 0, stream>>>(ei, pos, x, Wtp, W1, b1, W2, b2,
                                              (float*)d_out, E, N);
        k_add_x<<<1024, 256, 0, stream>>>(x, (float*)d_out, N * C);
    }
}